// Round 6
// baseline (82.400 us; speedup 1.0000x reference)
//
#include <hip/hip_runtime.h>
#include <hip/hip_bf16.h>
#include <cfloat>

#define BB 16
#define NN 512
#define DIMX 78
#define NH 6
#define DHH 13
#define QS 16                      // padded head-dim stride for q/k/v
#define NC (NH*3*DHH)              // 234
#define SCALE 0.27735009811261457f // 13^-0.5
#define LAM_A 1.0f
#define LAM_G 0.5f
#define NU 32

typedef unsigned short ushortx;
typedef ushortx ushort8 __attribute__((ext_vector_type(8)));

__device__ __forceinline__ ushortx f2bf(float f) {
  unsigned u = __float_as_uint(f);
  unsigned r = (u + 0x7FFFu + ((u >> 16) & 1u)) >> 16;
  return (ushortx)r;
}
__device__ __forceinline__ float bf2f(ushortx h) {
  return __uint_as_float(((unsigned)h) << 16);
}

// ---------------- QKV projection: (B*N, 78) @ (78, 234) ----------------
// thread = 4 rows x 4 cols register tile; outputs padded to stride QS=16.
__global__ __launch_bounds__(256) void qkv_kernel(
    const float* __restrict__ x, const float* __restrict__ Wqkv,
    float* __restrict__ q, float* __restrict__ k, float* __restrict__ v) {
  int idx = blockIdx.x * 256 + threadIdx.x;
  const int NQ = 59;
  int rq = idx / NQ, cq = idx % NQ;
  if (rq >= (BB * NN) / 4) return;
  int c0 = cq * 4; if (c0 > NC - 4) c0 = NC - 4;
  int r0 = rq * 4;
  const float* x0 = x + (size_t)r0 * DIMX;

  float acc[4][4];
#pragma unroll
  for (int r = 0; r < 4; ++r)
#pragma unroll
    for (int c = 0; c < 4; ++c) acc[r][c] = 0.f;

#pragma unroll 6
  for (int d = 0; d < DIMX; ++d) {
    float w0 = Wqkv[d * NC + c0 + 0];
    float w1 = Wqkv[d * NC + c0 + 1];
    float w2 = Wqkv[d * NC + c0 + 2];
    float w3 = Wqkv[d * NC + c0 + 3];
#pragma unroll
    for (int r = 0; r < 4; ++r) {
      float xv = x0[r * DIMX + d];
      acc[r][0] = fmaf(xv, w0, acc[r][0]);
      acc[r][1] = fmaf(xv, w1, acc[r][1]);
      acc[r][2] = fmaf(xv, w2, acc[r][2]);
      acc[r][3] = fmaf(xv, w3, acc[r][3]);
    }
  }
#pragma unroll
  for (int r = 0; r < 4; ++r) {
    int bn = r0 + r;
    int b = bn / NN, n = bn % NN;
#pragma unroll
    for (int c = 0; c < 4; ++c) {
      int col = c0 + c;
      int h  = col / (3 * DHH);
      int rm = col % (3 * DHH);
      int t  = rm / DHH;
      int dd = rm % DHH;
      float* dst = (t == 0) ? q : ((t == 1) ? k : v);
      dst[(((size_t)b * NH + h) * NN + n) * QS + dd] = acc[r][c];
    }
  }
}

// ---------------- Fused masked softmax attention ----------------
// grid = B*H*(N/64) = 768 blocks; block = 256 (4 waves), 3 blocks/CU.
// Pipelined: next row-group's q loads + adj gathers issue before current
// body; sched_barrier(0) pins the issue point so hipcc can't sink them.
__global__ __launch_bounds__(256, 3) void attn_kernel(
    const float* __restrict__ q, const float* __restrict__ k,
    const float* __restrict__ v, const int* __restrict__ mask,
    const float* __restrict__ adj, float* __restrict__ att) {
  __shared__ ushort8 k0s[NN], k1s[NN];
  __shared__ ushort8 v0s[NN], v1s[NN];
  __shared__ short jact[NN];
  __shared__ unsigned char ract[64];
  __shared__ float vsum[DHH];
  __shared__ float vpart_s[2][DHH];
  __shared__ int nact_s, nract_s;

  int blk   = blockIdx.x;
  int itile = blk & 7;
  int bh    = blk >> 3;
  int b     = bh / NH;
  int h     = bh % NH;
  int i0    = itile * 64;

  const float* kb = k + (size_t)bh * NN * QS;
  const float* vb = v + (size_t)bh * NN * QS;
  const int* mrow = mask + b * NN;

  int tid  = threadIdx.x;
  int wave = tid >> 6, lane = tid & 63;

  if (wave == 0) {
    unsigned m8 = 0;
#pragma unroll
    for (int t = 0; t < 8; ++t) {
      int j = lane * 8 + t;
      if (mrow[j] != 0) m8 |= (1u << t);
    }
    int cnt = __popc(m8);
    int pre = cnt;
#pragma unroll
    for (int off = 1; off < 64; off <<= 1) {
      int o = __shfl_up(pre, off);
      if (lane >= off) pre += o;
    }
    pre -= cnt;
    int w = pre;
#pragma unroll
    for (int t = 0; t < 8; ++t)
      if ((m8 >> t) & 1) jact[w++] = (short)(lane * 8 + t);
    if (lane == 63) nact_s = pre + cnt;
  } else if (wave == 1) {
    int a = (mrow[i0 + lane] != 0) ? 1 : 0;
    int pre = a;
#pragma unroll
    for (int off = 1; off < 64; off <<= 1) {
      int o = __shfl_up(pre, off);
      if (lane >= off) pre += o;
    }
    pre -= a;
    if (a) ract[pre] = (unsigned char)lane;
    if (lane == 63) nract_s = pre + a;
  } else {
    // waves 2,3: parallel vsum partials (4 rows per thread, butterfly)
    int idx2 = (wave - 2) * 64 + lane;  // 0..127
    float vp[DHH];
#pragma unroll
    for (int d = 0; d < DHH; ++d) vp[d] = 0.f;
#pragma unroll
    for (int rep = 0; rep < 4; ++rep) {
      const float* vr = vb + (size_t)(idx2 + rep * 128) * QS;
      float4 f0 = *(const float4*)(vr);
      float4 f1 = *(const float4*)(vr + 4);
      float4 f2 = *(const float4*)(vr + 8);
      float f12 = vr[12];
      vp[0] += f0.x; vp[1] += f0.y; vp[2] += f0.z; vp[3] += f0.w;
      vp[4] += f1.x; vp[5] += f1.y; vp[6] += f1.z; vp[7] += f1.w;
      vp[8] += f2.x; vp[9] += f2.y; vp[10] += f2.z; vp[11] += f2.w;
      vp[12] += f12;
    }
#pragma unroll
    for (int off = 1; off < 64; off <<= 1)
#pragma unroll
      for (int d = 0; d < DHH; ++d) vp[d] += __shfl_xor(vp[d], off);
    if (lane < DHH) vpart_s[wave - 2][lane] = vp[lane];
  }
  __syncthreads();

  int na = nact_s;
  int nr = nract_s;

  // stage compacted K,V as bf16 (vectorized source loads); zero tails
  for (int t = tid; t < NN; t += 256) {
    if (t < na) {
      int j = jact[t];
      const float4* kr4 = (const float4*)(kb + (size_t)j * QS);
      const float4* vr4 = (const float4*)(vb + (size_t)j * QS);
      float4 kf0 = kr4[0], kf1 = kr4[1], kf2 = kr4[2];
      float4 vf0 = vr4[0], vf1 = vr4[1], vf2 = vr4[2];
      float k12 = kb[(size_t)j * QS + 12];
      float v12 = vb[(size_t)j * QS + 12];
      ushort8 a0, a1, c0v, c1;
      a0[0]=f2bf(kf0.x); a0[1]=f2bf(kf0.y); a0[2]=f2bf(kf0.z); a0[3]=f2bf(kf0.w);
      a0[4]=f2bf(kf1.x); a0[5]=f2bf(kf1.y); a0[6]=f2bf(kf1.z); a0[7]=f2bf(kf1.w);
      a1[0]=f2bf(kf2.x); a1[1]=f2bf(kf2.y); a1[2]=f2bf(kf2.z); a1[3]=f2bf(kf2.w);
      a1[4]=f2bf(k12);   a1[5]=0; a1[6]=0; a1[7]=0;
      c0v[0]=f2bf(vf0.x); c0v[1]=f2bf(vf0.y); c0v[2]=f2bf(vf0.z); c0v[3]=f2bf(vf0.w);
      c0v[4]=f2bf(vf1.x); c0v[5]=f2bf(vf1.y); c0v[6]=f2bf(vf1.z); c0v[7]=f2bf(vf1.w);
      c1[0]=f2bf(vf2.x); c1[1]=f2bf(vf2.y); c1[2]=f2bf(vf2.z); c1[3]=f2bf(vf2.w);
      c1[4]=f2bf(v12);   c1[5]=0; c1[6]=0; c1[7]=0;
      k0s[t] = a0; k1s[t] = a1; v0s[t] = c0v; v1s[t] = c1;
    } else {
      ushort8 z = (ushort8)0;
      k0s[t] = z; k1s[t] = z; v0s[t] = z; v1s[t] = z;
      jact[t] = 0;
    }
  }
  if (tid < DHH) vsum[tid] = vpart_s[0][tid] + vpart_s[1][tid];
  __syncthreads();

  // fully-masked rows: uniform softmax over all 512, zero adjacency
  for (int e = tid; e < 64 * DHH; e += 256) {
    int r = e / DHH, d = e % DHH;
    int i = i0 + r;
    if (mrow[i] == 0)
      att[((size_t)b * NN + i) * DIMX + h * DHH + d] = (LAM_A / 512.f) * vsum[d];
  }

  int grp = lane >> 4;
  int li  = lane & 15;

// issue q + adj loads for row-group starting at `nb` into (AJ, Q0..Q2, Q12)
#define PREFETCH(nb, AJ, Q0, Q1, Q2, Q12)                       \
  {                                                             \
    int pr = (nb) + grp;                                        \
    int pi = i0 + ract[(pr < nr) ? pr : 0];                     \
    const float* qp = q + ((size_t)bh * NN + pi) * QS;          \
    Q0 = *(const float4*)(qp);                                  \
    Q1 = *(const float4*)(qp + 4);                              \
    Q2 = *(const float4*)(qp + 8);                              \
    Q12 = qp[12];                                               \
    const float* ar = adj + ((size_t)b * NN + pi) * NN;         \
    _Pragma("unroll")                                           \
    for (int u = 0; u < NU; ++u)                                \
      if (u * 16 < na) AJ[u] = ar[jact[u * 16 + li]];           \
  }

  float ajc[NU], ajn[NU];
  float4 qc0, qc1, qc2, qn0, qn1, qn2;
  float qc12, qn12;

  int base = wave * 4;
  if (base < nr) PREFETCH(base, ajc, qc0, qc1, qc2, qc12);

  for (; base < nr; base += 16) {
    bool has_next = (base + 16) < nr;  // wave-uniform
    if (has_next) PREFETCH(base + 16, ajn, qn0, qn1, qn2, qn12);
    __builtin_amdgcn_sched_barrier(0);  // pin prefetch issue point

    int ridx = base + grp;
    bool rok = ridx < nr;
    int i = i0 + ract[rok ? ridx : 0];
    float qreg[DHH] = {qc0.x, qc0.y, qc0.z, qc0.w,
                       qc1.x, qc1.y, qc1.z, qc1.w,
                       qc2.x, qc2.y, qc2.z, qc2.w, qc12};

    float s[NU];
    float mx = -FLT_MAX;
#pragma unroll
    for (int u = 0; u < NU; ++u) {
      if (u * 16 < na) {  // wave-uniform branch
        int t = u * 16 + li;
        ushort8 ka = k0s[t];
        ushort8 kc = k1s[t];
        float dot = 0.f;
#pragma unroll
        for (int d = 0; d < 8; ++d) dot = fmaf(qreg[d], bf2f(ka[d]), dot);
#pragma unroll
        for (int d = 0; d < 5; ++d) dot = fmaf(qreg[8 + d], bf2f(kc[d]), dot);
        s[u] = (t < na) ? dot * SCALE : -FLT_MAX;
        mx = fmaxf(mx, s[u]);
      }
    }
#pragma unroll
    for (int off = 1; off < 16; off <<= 1) mx = fmaxf(mx, __shfl_xor(mx, off));

    float sum = 0.f;
#pragma unroll
    for (int u = 0; u < NU; ++u) {
      if (u * 16 < na) {
        float p = __expf(s[u] - mx);
        s[u] = p;
        sum += p;
      }
    }
#pragma unroll
    for (int off = 1; off < 16; off <<= 1) sum += __shfl_xor(sum, off);
    float inv = LAM_A / sum;

    float acc[DHH];
#pragma unroll
    for (int d = 0; d < DHH; ++d) acc[d] = 0.f;
#pragma unroll
    for (int u = 0; u < NU; ++u) {
      if (u * 16 < na) {
        int t = u * 16 + li;
        ushort8 va = v0s[t];
        ushort8 vc = v1s[t];
        float wu = fmaf(LAM_G, ajc[u], s[u] * inv);  // tail rows: v==0 -> 0
#pragma unroll
        for (int d = 0; d < 8; ++d) acc[d] = fmaf(wu, bf2f(va[d]), acc[d]);
#pragma unroll
        for (int d = 0; d < 5; ++d) acc[8 + d] = fmaf(wu, bf2f(vc[d]), acc[8 + d]);
      }
    }
#pragma unroll
    for (int off = 1; off < 16; off <<= 1) {
#pragma unroll
      for (int d = 0; d < DHH; ++d) acc[d] += __shfl_xor(acc[d], off);
    }

    if (rok && li == 0) {
#pragma unroll
      for (int d = 0; d < DHH; ++d)
        att[((size_t)b * NN + i) * DIMX + h * DHH + d] = acc[d];
    }

    if (has_next) {  // rotate pipeline registers (wave-uniform)
#pragma unroll
      for (int u = 0; u < NU; ++u)
        if (u * 16 < na) ajc[u] = ajn[u];
      qc0 = qn0; qc1 = qn1; qc2 = qn2; qc12 = qn12;
    }
  }
#undef PREFETCH
}

// ---------------- Output projection: (B*N,78) @ (78,78) + b ----------------
// block = 320 threads (5 waves), 32 rows/block, thread = 2 rows x 4 cols.
__global__ __launch_bounds__(320) void proj_kernel(
    const float* __restrict__ att, const float* __restrict__ Wout,
    const float* __restrict__ bout, float* __restrict__ out) {
  __shared__ float Ws[DIMX][80];   // padded cols
  __shared__ float as[32][82];     // stride 82: conflict-free row reads
  __shared__ float bs[80];
  int tid = threadIdx.x;
  for (int e = tid; e < DIMX * 80; e += 320) {
    int r = e / 80, c = e % 80;
    Ws[r][c] = (c < DIMX) ? Wout[r * DIMX + c] : 0.f;
  }
  if (tid < 80) bs[tid] = (tid < DIMX) ? bout[tid] : 0.f;
  size_t row0 = (size_t)blockIdx.x * 32;
  for (int e = tid; e < 32 * DIMX; e += 320)
    as[e / DIMX][e % DIMX] = att[row0 * DIMX + e];
  __syncthreads();

  int r2 = tid / 20;   // 0..15 -> rows r2*2, r2*2+1
  int cq = tid % 20;   // 0..19 -> cols cq*4..cq*4+3 (last quad: 2 pad)
  int c0 = cq * 4;
  float acc0[4], acc1[4];
#pragma unroll
  for (int kk = 0; kk < 4; ++kk) { acc0[kk] = bs[c0 + kk]; acc1[kk] = bs[c0 + kk]; }

#pragma unroll 6
  for (int d = 0; d < DIMX; ++d) {
    float4 w = *(const float4*)&Ws[d][c0];
    float a0 = as[r2 * 2 + 0][d];
    float a1 = as[r2 * 2 + 1][d];
    acc0[0] = fmaf(a0, w.x, acc0[0]); acc0[1] = fmaf(a0, w.y, acc0[1]);
    acc0[2] = fmaf(a0, w.z, acc0[2]); acc0[3] = fmaf(a0, w.w, acc0[3]);
    acc1[0] = fmaf(a1, w.x, acc1[0]); acc1[1] = fmaf(a1, w.y, acc1[1]);
    acc1[2] = fmaf(a1, w.z, acc1[2]); acc1[3] = fmaf(a1, w.w, acc1[3]);
  }

  size_t r0o = (row0 + r2 * 2) * (size_t)DIMX;
  *(float2*)&out[r0o + c0]        = make_float2(acc0[0], acc0[1]);
  *(float2*)&out[r0o + DIMX + c0] = make_float2(acc1[0], acc1[1]);
  if (cq < 19) {
    *(float2*)&out[r0o + c0 + 2]        = make_float2(acc0[2], acc0[3]);
    *(float2*)&out[r0o + DIMX + c0 + 2] = make_float2(acc1[2], acc1[3]);
  }
}

extern "C" void kernel_launch(void* const* d_in, const int* in_sizes, int n_in,
                              void* d_out, int out_size, void* d_ws, size_t ws_size,
                              hipStream_t stream) {
  const float* x    = (const float*)d_in[0];
  const int*   mask = (const int*)d_in[1];
  const float* adj  = (const float*)d_in[2];
  const float* Wqkv = (const float*)d_in[3];
  const float* Wout = (const float*)d_in[4];
  const float* bout = (const float*)d_in[5];
  float* out = (float*)d_out;

  const size_t qkv_elems = (size_t)BB * NH * NN * QS;  // 786,432 (padded)
  float* q   = (float*)d_ws;
  float* k   = q + qkv_elems;
  float* v   = k + qkv_elems;
  float* att = v + qkv_elems;  // B*N*78

  const int NQ = 59;
  int qkv_threads = (BB * NN / 4) * NQ;
  qkv_kernel<<<(qkv_threads + 255) / 256, 256, 0, stream>>>(x, Wqkv, q, k, v);
  attn_kernel<<<BB * NH * (NN / 64), 256, 0, stream>>>(q, k, v, mask, adj, att);
  proj_kernel<<<BB * NN / 32, 320, 0, stream>>>(att, Wout, bout, out);
}